// Round 1
// baseline (182.151 us; speedup 1.0000x reference)
//
#include <hip/hip_runtime.h>
#include <math.h>

#define BATCH 32
#define TH    256
#define TQn   64
#define DIN   256
#define DD    256   // INTERNAL
#define QT    8
#define KB    32
#define LDP   132   // 128 + 4 pad (keeps 16B alignment of rows: 132*4=528=33*16)

__device__ __forceinline__ float readlane_f(float x, int l) {
    return __int_as_float(__builtin_amdgcn_readlane(__float_as_int(x), l));
}

// ---------------------------------------------------------------------------
// Kernel 1: projections (two fp32 GEMMs, K=256)
//   blocks 0..127 : kpT[b][d][t] = sum_i keys[b*TH+t][i] * w1[d][i]  (transposed store)
//   blocks 128..159: qp[r][d]    = sum_i state[r][i]     * w2[d][i]
// tile 128(M) x 128(N), 256 threads, 8x8 micro-tile, K chunks of 32.
// ---------------------------------------------------------------------------
__global__ __launch_bounds__(256, 1)
void proj_kernel(const float* __restrict__ keys,
                 const float* __restrict__ state,
                 const float* __restrict__ w1,
                 const float* __restrict__ w2,
                 float* __restrict__ kpT,
                 float* __restrict__ qpo)
{
    __shared__ float sA[KB][LDP];
    __shared__ float sB[KB][LDP];

    const int bid = blockIdx.x;
    const int tid = threadIdx.x;

    const float* X;
    const float* W;
    int m0, n0;
    bool is_kp;
    if (bid < 128) {
        is_kp = true;
        m0 = (bid >> 1) * 128;
        n0 = (bid & 1) * 128;
        X = keys; W = w1;
    } else {
        is_kp = false;
        int lb = bid - 128;
        m0 = (lb >> 1) * 128;
        n0 = (lb & 1) * 128;
        X = state; W = w2;
    }

    const int tx = tid & 15;   // n-group
    const int ty = tid >> 4;   // m-group
    const int lr = tid >> 3;   // staging row 0..31
    const int kc = tid & 7;    // staging k-quad 0..7

    float acc[8][8];
    #pragma unroll
    for (int i = 0; i < 8; i++)
        #pragma unroll
        for (int j = 0; j < 8; j++) acc[i][j] = 0.f;

    for (int k0 = 0; k0 < DIN; k0 += KB) {
        // stage A: sA[k][m] = X[m0+m][k0+k]  (transpose via scalar LDS stores)
        #pragma unroll
        for (int rr = 0; rr < 4; rr++) {
            int row = rr * 32 + lr;
            float4 g = *(const float4*)&X[(size_t)(m0 + row) * DIN + k0 + kc * 4];
            sA[kc * 4 + 0][row] = g.x;
            sA[kc * 4 + 1][row] = g.y;
            sA[kc * 4 + 2][row] = g.z;
            sA[kc * 4 + 3][row] = g.w;
        }
        // stage B: sB[k][n] = W[n0+n][k0+k]
        #pragma unroll
        for (int rr = 0; rr < 4; rr++) {
            int n = rr * 32 + lr;
            float4 g = *(const float4*)&W[(size_t)(n0 + n) * DIN + k0 + kc * 4];
            sB[kc * 4 + 0][n] = g.x;
            sB[kc * 4 + 1][n] = g.y;
            sB[kc * 4 + 2][n] = g.z;
            sB[kc * 4 + 3][n] = g.w;
        }
        __syncthreads();

        #pragma unroll 8
        for (int k = 0; k < KB; k++) {
            float a[8], bb[8];
            *(float4*)&a[0]  = *(float4*)&sA[k][ty * 8];
            *(float4*)&a[4]  = *(float4*)&sA[k][ty * 8 + 4];
            *(float4*)&bb[0] = *(float4*)&sB[k][tx * 8];
            *(float4*)&bb[4] = *(float4*)&sB[k][tx * 8 + 4];
            #pragma unroll
            for (int i = 0; i < 8; i++)
                #pragma unroll
                for (int j = 0; j < 8; j++)
                    acc[i][j] = fmaf(a[i], bb[j], acc[i][j]);
        }
        __syncthreads();
    }

    if (is_kp) {
        // transposed store: kpT[b][d][t]; 16B-dense chunks, 64B-line efficient
        const int b  = m0 >> 8;
        const int t0 = m0 & 255;
        #pragma unroll
        for (int j = 0; j < 8; j++) {
            int d = n0 + tx * 8 + j;
            float* p = kpT + ((size_t)b * DD + d) * TH + t0 + ty * 8;
            *(float4*)(p)     = make_float4(acc[0][j], acc[1][j], acc[2][j], acc[3][j]);
            *(float4*)(p + 4) = make_float4(acc[4][j], acc[5][j], acc[6][j], acc[7][j]);
        }
    } else {
        #pragma unroll
        for (int i = 0; i < 8; i++) {
            int r = m0 + ty * 8 + i;
            float* p = qpo + (size_t)r * DD + n0 + tx * 8;
            *(float4*)(p)     = make_float4(acc[i][0], acc[i][1], acc[i][2], acc[i][3]);
            *(float4*)(p + 4) = make_float4(acc[i][4], acc[i][5], acc[i][6], acc[i][7]);
        }
    }
}

// ---------------------------------------------------------------------------
// Kernel 2: fused scores + softmax + context.
// One block per (b, q-tile of 8). 256 threads: thread = t in score phase,
// thread = output feature i in context phase. Wave-uniform operands come from
// registers via v_readlane (avoids LDS-broadcast bottleneck).
// ---------------------------------------------------------------------------
__global__ __launch_bounds__(256, 1)
void attn_kernel(const float* __restrict__ keys,
                 const float* __restrict__ vvec,
                 const float* __restrict__ kpT,
                 const float* __restrict__ qp,
                 float* __restrict__ out)
{
    __shared__ float s_alpha[QT][TH];   // scores -> unnormalized alpha
    __shared__ float s_rsum[QT];

    const int b    = blockIdx.x >> 3;
    const int q0   = (blockIdx.x & 7) * QT;
    const int tid  = threadIdx.x;
    const int lane = tid & 63;
    const int wv   = tid >> 6;

    // ---- scores: acc[q] = sum_d v[d] * tanh(qp[q][d] + kp[d][t=tid]) ----
    float acc[QT];
    #pragma unroll
    for (int q = 0; q < QT; q++) acc[q] = 0.f;

    const float* kbase = kpT + (size_t)b * DD * TH + tid;
    const float* qpb   = qp + (size_t)(b * TQn + q0) * DD;

    for (int c = 0; c < 4; c++) {
        float qpr[QT];
        #pragma unroll
        for (int q = 0; q < QT; q++)
            qpr[q] = qpb[q * DD + c * 64 + lane] * 2.f;   // prescale by 2 for tanh
        float vr = vvec[c * 64 + lane];

        for (int l = 0; l < 64; l += 4) {
            float kv4[4];
            #pragma unroll
            for (int j = 0; j < 4; j++)
                kv4[j] = kbase[(size_t)(c * 64 + l + j) * TH] * 2.f;
            #pragma unroll
            for (int j = 0; j < 4; j++) {
                float vd = readlane_f(vr, l + j);
                float kv = kv4[j];
                #pragma unroll
                for (int q = 0; q < QT; q++) {
                    // tanh(x) = 1 - 2/(exp(2x)+1); args prescaled by 2
                    float x = readlane_f(qpr[q], l + j) + kv;
                    float e = __expf(x);
                    float r = __builtin_amdgcn_rcpf(e + 1.f);
                    acc[q] = fmaf(vd, fmaf(-2.f, r, 1.f), acc[q]);
                }
            }
        }
    }

    #pragma unroll
    for (int q = 0; q < QT; q++) s_alpha[q][tid] = acc[q];
    __syncthreads();

    // ---- softmax over t (axis 256). wave wv handles q = 2*wv, 2*wv+1 ----
    #pragma unroll
    for (int r = 0; r < 2; r++) {
        int q = wv * 2 + r;
        float x0 = s_alpha[q][lane];
        float x1 = s_alpha[q][lane + 64];
        float x2 = s_alpha[q][lane + 128];
        float x3 = s_alpha[q][lane + 192];
        float m = fmaxf(fmaxf(x0, x1), fmaxf(x2, x3));
        #pragma unroll
        for (int off = 32; off >= 1; off >>= 1) m = fmaxf(m, __shfl_xor(m, off));
        float e0 = __expf(x0 - m), e1 = __expf(x1 - m);
        float e2 = __expf(x2 - m), e3 = __expf(x3 - m);
        s_alpha[q][lane]       = e0;
        s_alpha[q][lane + 64]  = e1;
        s_alpha[q][lane + 128] = e2;
        s_alpha[q][lane + 192] = e3;
        float s = (e0 + e1) + (e2 + e3);
        #pragma unroll
        for (int off = 32; off >= 1; off >>= 1) s += __shfl_xor(s, off);
        if (lane == 0) s_rsum[q] = 1.f / s;
    }
    __syncthreads();

    // ---- context: ctx[q][i=tid] = (1/sum_q) * sum_t alpha[q][t]*keys[b][t][i]
    float ctx[QT];
    #pragma unroll
    for (int q = 0; q < QT; q++) ctx[q] = 0.f;

    const float* krow = keys + (size_t)b * TH * DIN + tid;
    for (int c = 0; c < 4; c++) {
        float ar[QT];
        #pragma unroll
        for (int q = 0; q < QT; q++) ar[q] = s_alpha[q][c * 64 + lane];
        for (int l = 0; l < 64; l += 4) {
            float kv4[4];
            #pragma unroll
            for (int j = 0; j < 4; j++)
                kv4[j] = krow[(size_t)(c * 64 + l + j) * DIN];
            #pragma unroll
            for (int j = 0; j < 4; j++) {
                #pragma unroll
                for (int q = 0; q < QT; q++)
                    ctx[q] = fmaf(readlane_f(ar[q], l + j), kv4[j], ctx[q]);
            }
        }
    }

    #pragma unroll
    for (int q = 0; q < QT; q++)
        out[(size_t)(b * TQn + q0 + q) * DIN + tid] = ctx[q] * s_rsum[q];
}

// ---------------------------------------------------------------------------
extern "C" void kernel_launch(void* const* d_in, const int* in_sizes, int n_in,
                              void* d_out, int out_size, void* d_ws, size_t ws_size,
                              hipStream_t stream) {
    (void)in_sizes; (void)n_in; (void)out_size; (void)ws_size;
    const float* keys  = (const float*)d_in[0];  // [32*256][256]
    const float* state = (const float*)d_in[1];  // [32*64][256]
    const float* w1    = (const float*)d_in[2];  // [256][256]
    const float* w2    = (const float*)d_in[3];  // [256][256]
    const float* v     = (const float*)d_in[4];  // [256]
    float* out = (float*)d_out;                  // [2048][256]

    float* kpT = (float*)d_ws;                         // 32*256*256 = 8 MB
    float* qp  = kpT + (size_t)BATCH * DD * TH;        // 2048*256   = 2 MB

    hipLaunchKernelGGL(proj_kernel, dim3(160), dim3(256), 0, stream,
                       keys, state, w1, w2, kpT, qp);
    hipLaunchKernelGGL(attn_kernel, dim3(BATCH * (TQn / QT)), dim3(256), 0, stream,
                       keys, v, kpT, qp, out);
}

// Round 2
// 153.725 us; speedup vs baseline: 1.1849x; 1.1849x over previous
//
#include <hip/hip_runtime.h>
#include <math.h>

#define BATCH 32
#define TH    256
#define TQn   64
#define DIN   256
#define DD    256   // INTERNAL
#define QT    8
#define KB    32
#define LDP   68    // 64 + 4 pad: rows stay 16B-aligned (68*4=272=17*16)
#define E2C   2.885390081777927f   // 2*log2(e): exp(2x) == exp2(x*E2C)

__device__ __forceinline__ float readlane_f(float x, int l) {
    return __int_as_float(__builtin_amdgcn_readlane(__float_as_int(x), l));
}

// ---------------------------------------------------------------------------
// Kernel 1: projections (two fp32 GEMMs, K=256), 64x64 tile, 256 thr, 4x4 micro
//   blocks 0..511  : kpT[b][d][t] = sum_i keys[b*TH+t][i] * w1[d][i]  (transposed)
//   blocks 512..639: qp[r][d]     = sum_i state[r][i]     * w2[d][i]
// 640 blocks -> ~2.5 blocks/CU -> 10 waves/CU (vs 160 blocks before).
// ---------------------------------------------------------------------------
__global__ __launch_bounds__(256, 4)
void proj_kernel(const float* __restrict__ keys,
                 const float* __restrict__ state,
                 const float* __restrict__ w1,
                 const float* __restrict__ w2,
                 float* __restrict__ kpT,
                 float* __restrict__ qpo)
{
    __shared__ float sA[KB][LDP];
    __shared__ float sB[KB][LDP];

    const int bid = blockIdx.x;
    const int tid = threadIdx.x;

    const float* X;
    const float* W;
    int m0, n0;
    bool is_kp;
    if (bid < 512) {
        is_kp = true;
        m0 = (bid >> 2) * 64;
        n0 = (bid & 3) * 64;
        X = keys; W = w1;
    } else {
        is_kp = false;
        int lb = bid - 512;
        m0 = (lb >> 2) * 64;
        n0 = (lb & 3) * 64;
        X = state; W = w2;
    }

    const int tx = tid & 15;   // n-group (4 cols)
    const int ty = tid >> 4;   // m-group (4 rows)
    const int lr = tid >> 3;   // staging row 0..31
    const int kc = tid & 7;    // staging k-quad 0..7

    float acc[4][4];
    #pragma unroll
    for (int i = 0; i < 4; i++)
        #pragma unroll
        for (int j = 0; j < 4; j++) acc[i][j] = 0.f;

    for (int k0 = 0; k0 < DIN; k0 += KB) {
        // stage A: sA[k][m] = X[m0+m][k0+k]  (64 rows, 2 passes of 32)
        #pragma unroll
        for (int rr = 0; rr < 2; rr++) {
            int row = rr * 32 + lr;
            float4 g = *(const float4*)&X[(size_t)(m0 + row) * DIN + k0 + kc * 4];
            sA[kc * 4 + 0][row] = g.x;
            sA[kc * 4 + 1][row] = g.y;
            sA[kc * 4 + 2][row] = g.z;
            sA[kc * 4 + 3][row] = g.w;
        }
        // stage B: sB[k][n] = W[n0+n][k0+k]
        #pragma unroll
        for (int rr = 0; rr < 2; rr++) {
            int n = rr * 32 + lr;
            float4 g = *(const float4*)&W[(size_t)(n0 + n) * DIN + k0 + kc * 4];
            sB[kc * 4 + 0][n] = g.x;
            sB[kc * 4 + 1][n] = g.y;
            sB[kc * 4 + 2][n] = g.z;
            sB[kc * 4 + 3][n] = g.w;
        }
        __syncthreads();

        #pragma unroll 8
        for (int k = 0; k < KB; k++) {
            float a[4], bb[4];
            *(float4*)&a[0]  = *(float4*)&sA[k][ty * 4];
            *(float4*)&bb[0] = *(float4*)&sB[k][tx * 4];
            #pragma unroll
            for (int i = 0; i < 4; i++)
                #pragma unroll
                for (int j = 0; j < 4; j++)
                    acc[i][j] = fmaf(a[i], bb[j], acc[i][j]);
        }
        __syncthreads();
    }

    if (is_kp) {
        // transposed store: kpT[b][d][t]; 16B-dense chunks
        const int b  = m0 >> 8;
        const int t0 = m0 & 255;
        #pragma unroll
        for (int j = 0; j < 4; j++) {
            int d = n0 + tx * 4 + j;
            float* p = kpT + ((size_t)b * DD + d) * TH + t0 + ty * 4;
            *(float4*)p = make_float4(acc[0][j], acc[1][j], acc[2][j], acc[3][j]);
        }
    } else {
        #pragma unroll
        for (int i = 0; i < 4; i++) {
            int r = m0 + ty * 4 + i;
            float* p = qpo + (size_t)r * DD + n0 + tx * 4;
            *(float4*)p = make_float4(acc[i][0], acc[i][1], acc[i][2], acc[i][3]);
        }
    }
}

// ---------------------------------------------------------------------------
// Kernel 2: fused scores + softmax + context. 1024 threads/block.
// Score phase:  thread = (t = tid&255, d-quarter = tid>>8); partials in LDS.
// tanh eliminated: score = Sv - 2*sum_d v_d*sigmoid(-2x); Sv cancels in softmax
//   -> softmax input is -2 * sum_d v_d / (exp2(E2C*x)+1)
// Context phase: thread = (i = tid&255, t-quarter = tid>>8); partials in LDS.
// Grid 256, b = bid&31 -> all 8 q-tiles of a batch on one XCD (L2 locality).
// ---------------------------------------------------------------------------
__global__ __launch_bounds__(1024, 4)
void attn_kernel(const float* __restrict__ keys,
                 const float* __restrict__ vvec,
                 const float* __restrict__ kpT,
                 const float* __restrict__ qp,
                 float* __restrict__ out)
{
    __shared__ float s_part[4][QT][TH];   // 32 KB: score partials, then ctx partials
    __shared__ float s_alpha[QT][TH];     // 8 KB: unnormalized softmax weights
    __shared__ float s_rsum[QT];

    const int bid  = blockIdx.x;
    const int b    = bid & 31;            // bid%8 == b%8 -> XCD-local batch
    const int q0   = (bid >> 5) * QT;
    const int tid  = threadIdx.x;
    const int t    = tid & 255;
    const int dg   = tid >> 8;            // d-quarter (score) / t-quarter (ctx)
    const int lane = tid & 63;
    const int wv   = tid >> 6;

    // ---- scores (partial over 64 d's) ----
    float acc[QT];
    #pragma unroll
    for (int q = 0; q < QT; q++) acc[q] = 0.f;

    const float* kbase = kpT + ((size_t)b * DD + dg * 64) * TH + t;
    const float* qpb   = qp + (size_t)(b * TQn + q0) * DD + dg * 64;

    float qpr[QT];
    #pragma unroll
    for (int q = 0; q < QT; q++)
        qpr[q] = qpb[q * DD + lane] * E2C;      // prescaled for exp2
    float vr = vvec[dg * 64 + lane];

    for (int l = 0; l < 64; l += 4) {
        float kv4[4];
        #pragma unroll
        for (int j = 0; j < 4; j++)
            kv4[j] = kbase[(size_t)(l + j) * TH] * E2C;
        #pragma unroll
        for (int j = 0; j < 4; j++) {
            float vd = readlane_f(vr, l + j);
            float kv = kv4[j];
            #pragma unroll
            for (int q = 0; q < QT; q++) {
                float x = readlane_f(qpr[q], l + j) + kv;
                float e = __builtin_amdgcn_exp2f(x);
                float r = __builtin_amdgcn_rcpf(e + 1.f);
                acc[q] = fmaf(vd, r, acc[q]);     // sum_d v_d * sigmoid(-2x)
            }
        }
    }

    #pragma unroll
    for (int q = 0; q < QT; q++) s_part[dg][q][t] = acc[q];
    __syncthreads();

    // ---- softmax over t=256; wave wv (<8) handles q=wv ----
    if (wv < QT) {
        const int q = wv;
        float x0, x1, x2, x3;
        {
            float p0 = s_part[0][q][lane]       + s_part[1][q][lane]
                     + s_part[2][q][lane]       + s_part[3][q][lane];
            float p1 = s_part[0][q][lane + 64]  + s_part[1][q][lane + 64]
                     + s_part[2][q][lane + 64]  + s_part[3][q][lane + 64];
            float p2 = s_part[0][q][lane + 128] + s_part[1][q][lane + 128]
                     + s_part[2][q][lane + 128] + s_part[3][q][lane + 128];
            float p3 = s_part[0][q][lane + 192] + s_part[1][q][lane + 192]
                     + s_part[2][q][lane + 192] + s_part[3][q][lane + 192];
            x0 = -2.f * p0; x1 = -2.f * p1; x2 = -2.f * p2; x3 = -2.f * p3;
        }
        float m = fmaxf(fmaxf(x0, x1), fmaxf(x2, x3));
        #pragma unroll
        for (int off = 32; off >= 1; off >>= 1) m = fmaxf(m, __shfl_xor(m, off));
        float e0 = __expf(x0 - m), e1 = __expf(x1 - m);
        float e2 = __expf(x2 - m), e3 = __expf(x3 - m);
        s_alpha[q][lane]       = e0;
        s_alpha[q][lane + 64]  = e1;
        s_alpha[q][lane + 128] = e2;
        s_alpha[q][lane + 192] = e3;
        float s = (e0 + e1) + (e2 + e3);
        #pragma unroll
        for (int off = 32; off >= 1; off >>= 1) s += __shfl_xor(s, off);
        if (lane == 0) s_rsum[q] = 1.f / s;
    }
    __syncthreads();

    // ---- context (partial over 64 t's): ctx[q][i=t] ----
    float ctx[QT];
    #pragma unroll
    for (int q = 0; q < QT; q++) ctx[q] = 0.f;

    const float* krow = keys + ((size_t)b * TH + dg * 64) * DIN + t;
    float ar[QT];
    #pragma unroll
    for (int q = 0; q < QT; q++) ar[q] = s_alpha[q][dg * 64 + lane];

    for (int l = 0; l < 64; l += 4) {
        float kv4[4];
        #pragma unroll
        for (int j = 0; j < 4; j++)
            kv4[j] = krow[(size_t)(l + j) * DIN];
        #pragma unroll
        for (int j = 0; j < 4; j++) {
            #pragma unroll
            for (int q = 0; q < QT; q++)
                ctx[q] = fmaf(readlane_f(ar[q], l + j), kv4[j], ctx[q]);
        }
    }

    #pragma unroll
    for (int q = 0; q < QT; q++) s_part[dg][q][t] = ctx[q];
    __syncthreads();

    // ---- final reduce + normalize + store; 2 (q,i) pairs per thread ----
    #pragma unroll
    for (int p = tid; p < QT * TH; p += 1024) {
        int q = p >> 8, ii = p & 255;
        float s = s_part[0][q][ii] + s_part[1][q][ii]
                + s_part[2][q][ii] + s_part[3][q][ii];
        out[(size_t)(b * TQn + q0 + q) * DIN + ii] = s * s_rsum[q];
    }
}

// ---------------------------------------------------------------------------
extern "C" void kernel_launch(void* const* d_in, const int* in_sizes, int n_in,
                              void* d_out, int out_size, void* d_ws, size_t ws_size,
                              hipStream_t stream) {
    (void)in_sizes; (void)n_in; (void)out_size; (void)ws_size;
    const float* keys  = (const float*)d_in[0];  // [32*256][256]
    const float* state = (const float*)d_in[1];  // [32*64][256]
    const float* w1    = (const float*)d_in[2];  // [256][256]
    const float* w2    = (const float*)d_in[3];  // [256][256]
    const float* v     = (const float*)d_in[4];  // [256]
    float* out = (float*)d_out;                  // [2048][256]

    float* kpT = (float*)d_ws;                         // 32*256*256 = 8 MB
    float* qp  = kpT + (size_t)BATCH * DD * TH;        // 2048*256   = 2 MB

    hipLaunchKernelGGL(proj_kernel, dim3(640), dim3(256), 0, stream,
                       keys, state, w1, w2, kpT, qp);
    hipLaunchKernelGGL(attn_kernel, dim3(BATCH * (TQn / QT)), dim3(1024), 0, stream,
                       keys, v, kpT, qp, out);
}

// Round 3
// 127.539 us; speedup vs baseline: 1.4282x; 1.2053x over previous
//
#include <hip/hip_runtime.h>
#include <math.h>

#define BATCH 32
#define TH    256
#define TQn   64
#define DIN   256
#define DD    256   // INTERNAL
#define QT    4     // q's per attn block
#define E2C   2.885390081777927f   // 2*log2(e): exp(2x) == exp2(x*E2C)

typedef __attribute__((ext_vector_type(8)))  short bf16x8;   // 8 bf16 = 4 VGPRs
typedef __attribute__((ext_vector_type(16))) float floatx16;

__device__ __forceinline__ float readlane_f(float x, int l) {
    return __int_as_float(__builtin_amdgcn_readlane(__float_as_int(x), l));
}

// 2-term bf16 expansion of two floats, packed as (e0 low half | e1 high half).
// hi = bit-truncated bf16; lo = bf16(x - hi). |x - hi - lo| <= 2^-16 |x|.
__device__ __forceinline__ void split2(float x0, float x1, unsigned& hi, unsigned& lo) {
    unsigned u0 = __float_as_uint(x0), u1 = __float_as_uint(x1);
    unsigned h0 = u0 & 0xFFFF0000u,   h1 = u1 & 0xFFFF0000u;
    float r0 = x0 - __uint_as_float(h0);
    float r1 = x1 - __uint_as_float(h1);
    hi = (u0 >> 16) | h1;
    lo = (__float_as_uint(r0) >> 16) | (__float_as_uint(r1) & 0xFFFF0000u);
}

// Split an 8-wide fp32 group (two float4) into hi/lo bf16x8 fragments (uint4 each).
__device__ __forceinline__ void split8(float4 f0, float4 f1, uint4& hi, uint4& lo) {
    split2(f0.x, f0.y, hi.x, lo.x);
    split2(f0.z, f0.w, hi.y, lo.y);
    split2(f1.x, f1.y, hi.z, lo.z);
    split2(f1.z, f1.w, hi.w, lo.w);
}

// ---------------------------------------------------------------------------
// Kernel 1: projections via bf16-split MFMA (3x mfma_f32_32x32x16_bf16).
//   blocks 0..511  : kpT[b][d][t] = sum_i keys[b*TH+t][i] * w1[d][i]  (transposed)
//   blocks 512..639: qp[r][d]     = sum_i state[r][i]     * w2[d][i]
// Tile 64(m) x 64(n) x K64-chunks; 4 waves = 2x2 grid of 32x32 MFMA tiles.
// LDS in fragment order: region(part,half,s) of 65 uint4 (64 frags + 1 pad
// so s-regions hit distinct bank-quads); frag for lane l at +l*16B.
// ---------------------------------------------------------------------------
#define REG4  65                    // uint4 per region (64 + 1 pad)
#define WOFF  (16 * REG4)           // W base in uint4 units
__global__ __launch_bounds__(256, 4)
void proj_kernel(const float* __restrict__ keys,
                 const float* __restrict__ state,
                 const float* __restrict__ w1,
                 const float* __restrict__ w2,
                 float* __restrict__ kpT,
                 float* __restrict__ qpo)
{
    __shared__ uint4 lds4[2 * 16 * REG4];   // X: 16 regions, W: 16 regions = 32.5 KB

    const int bid = blockIdx.x;
    const int tid = threadIdx.x;

    const float* X;
    const float* W;
    int m0, n0;
    bool is_kp;
    if (bid < 512) {
        is_kp = true;
        m0 = (bid >> 2) * 64;
        n0 = (bid & 3) * 64;
        X = keys; W = w1;
    } else {
        is_kp = false;
        int lb = bid - 512;
        m0 = (lb >> 2) * 64;
        n0 = (lb & 3) * 64;
        X = state; W = w2;
    }

    const int w    = tid >> 6;        // wave 0..3
    const int l    = tid & 63;
    const int mt   = w >> 1;          // m half-tile of this wave
    const int nt   = w & 1;           // n half-tile
    // staging map: rows r and r+32, k-group kg (8 k's each)
    const int srow = tid >> 3;        // 0..31
    const int kg   = tid & 7;         // 0..7
    const int s_s  = kg >> 1;         // k-step 0..3
    const int lidx = (srow & 31) + 32 * (kg & 1);   // fragment lane slot

    floatx16 acc = {};

    for (int k0 = 0; k0 < DIN; k0 += 64) {
        // ---- stage X (64 rows x 64 k) and W (64 rows x 64 k), split to hi/lo ----
        #pragma unroll
        for (int hrow = 0; hrow < 2; hrow++) {
            int m = srow + hrow * 32;
            const float* px = X + (size_t)(m0 + m) * DIN + k0 + kg * 8;
            uint4 hi, lo;
            split8(*(const float4*)px, *(const float4*)(px + 4), hi, lo);
            int g = m >> 5;   // region half index
            lds4[((0 * 2 + g) * 4 + s_s) * REG4 + lidx] = hi;          // X hi
            lds4[((2 + g) * 4 + s_s) * REG4 + lidx] = lo;              // X lo
            const float* pw = W + (size_t)(n0 + m) * DIN + k0 + kg * 8;
            split8(*(const float4*)pw, *(const float4*)(pw + 4), hi, lo);
            lds4[WOFF + ((0 * 2 + g) * 4 + s_s) * REG4 + lidx] = hi;   // W hi
            lds4[WOFF + ((2 + g) * 4 + s_s) * REG4 + lidx] = lo;       // W lo
        }
        __syncthreads();

        // ---- 4 k-steps of 16, 3 MFMAs each ----
        #pragma unroll
        for (int s = 0; s < 4; s++) {
            uint4 ahr = lds4[((0 * 2 + mt) * 4 + s) * REG4 + l];
            uint4 alr = lds4[((2 + mt) * 4 + s) * REG4 + l];
            uint4 bhr = lds4[WOFF + ((0 * 2 + nt) * 4 + s) * REG4 + l];
            uint4 blr = lds4[WOFF + ((2 + nt) * 4 + s) * REG4 + l];
            bf16x8 ah = __builtin_bit_cast(bf16x8, ahr);
            bf16x8 al = __builtin_bit_cast(bf16x8, alr);
            bf16x8 bh = __builtin_bit_cast(bf16x8, bhr);
            bf16x8 bl = __builtin_bit_cast(bf16x8, blr);
            acc = __builtin_amdgcn_mfma_f32_32x32x16_bf16(ah, bh, acc, 0, 0, 0);
            acc = __builtin_amdgcn_mfma_f32_32x32x16_bf16(al, bh, acc, 0, 0, 0);
            acc = __builtin_amdgcn_mfma_f32_32x32x16_bf16(ah, bl, acc, 0, 0, 0);
        }
        __syncthreads();
    }

    // ---- epilogue. C/D: col=l&31 (n), row=(r&3)+8*(r>>2)+4*(l>>5) (m) ----
    const int col = l & 31;
    const int hl  = l >> 5;
    if (is_kp) {
        const int b  = m0 >> 8;
        const int tb = (m0 & 255) + mt * 32 + 4 * hl;
        const int d  = n0 + nt * 32 + col;
        float* p = kpT + ((size_t)b * DD + d) * TH + tb;
        #pragma unroll
        for (int g = 0; g < 4; g++)
            *(float4*)(p + 8 * g) = make_float4(acc[4*g], acc[4*g+1], acc[4*g+2], acc[4*g+3]);
    } else {
        const int d = n0 + nt * 32 + col;
        #pragma unroll
        for (int r = 0; r < 16; r++) {
            int row = (r & 3) + 8 * (r >> 2) + 4 * hl;
            qpo[(size_t)(m0 + mt * 32 + row) * DD + d] = acc[r];
        }
    }
}

// ---------------------------------------------------------------------------
// Kernel 2: fused scores + softmax + context. 1024 threads, grid 512
// (2 blocks/CU -> full 32-wave occupancy; R2 grid of 256 capped at 50%).
// Score phase:  thread = (t = tid&255, d-quarter = tid>>8); partials in LDS.
// tanh eliminated: score = Sv - 2*sum_d v_d*sigmoid(-2x); Sv cancels in softmax.
// Context phase: thread = (i = tid&255, t-quarter = tid>>8); partials in LDS.
// b = bid&31 -> all 16 q-tiles of a batch share an XCD (bid%8 == b%8).
// ---------------------------------------------------------------------------
__global__ __launch_bounds__(1024, 8)
void attn_kernel(const float* __restrict__ keys,
                 const float* __restrict__ vvec,
                 const float* __restrict__ kpT,
                 const float* __restrict__ qp,
                 float* __restrict__ out)
{
    __shared__ float s_part[4][QT][TH];   // 16 KB
    __shared__ float s_alpha[QT][TH];     // 4 KB
    __shared__ float s_rsum[QT];

    const int bid  = blockIdx.x;
    const int b    = bid & 31;
    const int q0   = (bid >> 5) * QT;
    const int tid  = threadIdx.x;
    const int t    = tid & 255;
    const int dg   = tid >> 8;            // d-quarter (score) / t-quarter (ctx)
    const int lane = tid & 63;
    const int wv   = tid >> 6;

    // ---- scores (partial over 64 d's) ----
    float acc[QT];
    #pragma unroll
    for (int q = 0; q < QT; q++) acc[q] = 0.f;

    const float* kbase = kpT + ((size_t)b * DD + dg * 64) * TH + t;
    const float* qpb   = qp + (size_t)(b * TQn + q0) * DD + dg * 64;

    float qpr[QT];
    #pragma unroll
    for (int q = 0; q < QT; q++)
        qpr[q] = qpb[q * DD + lane] * E2C;      // prescaled for exp2
    float vr = vvec[dg * 64 + lane];

    for (int l = 0; l < 64; l += 4) {
        float kv4[4];
        #pragma unroll
        for (int j = 0; j < 4; j++)
            kv4[j] = kbase[(size_t)(l + j) * TH] * E2C;
        #pragma unroll
        for (int j = 0; j < 4; j++) {
            float vd = readlane_f(vr, l + j);
            float kv = kv4[j];
            #pragma unroll
            for (int q = 0; q < QT; q++) {
                float x = readlane_f(qpr[q], l + j) + kv;
                float e = __builtin_amdgcn_exp2f(x);
                float r = __builtin_amdgcn_rcpf(e + 1.f);
                acc[q] = fmaf(vd, r, acc[q]);     // sum_d v_d * sigmoid(-2x)
            }
        }
    }

    #pragma unroll
    for (int q = 0; q < QT; q++) s_part[dg][q][t] = acc[q];
    __syncthreads();

    // ---- softmax over t=256; wave wv (<QT) handles q=wv ----
    if (wv < QT) {
        const int q = wv;
        float x0, x1, x2, x3;
        {
            float p0 = s_part[0][q][lane]       + s_part[1][q][lane]
                     + s_part[2][q][lane]       + s_part[3][q][lane];
            float p1 = s_part[0][q][lane + 64]  + s_part[1][q][lane + 64]
                     + s_part[2][q][lane + 64]  + s_part[3][q][lane + 64];
            float p2 = s_part[0][q][lane + 128] + s_part[1][q][lane + 128]
                     + s_part[2][q][lane + 128] + s_part[3][q][lane + 128];
            float p3 = s_part[0][q][lane + 192] + s_part[1][q][lane + 192]
                     + s_part[2][q][lane + 192] + s_part[3][q][lane + 192];
            x0 = -2.f * p0; x1 = -2.f * p1; x2 = -2.f * p2; x3 = -2.f * p3;
        }
        float m = fmaxf(fmaxf(x0, x1), fmaxf(x2, x3));
        #pragma unroll
        for (int off = 32; off >= 1; off >>= 1) m = fmaxf(m, __shfl_xor(m, off));
        float e0 = __expf(x0 - m), e1 = __expf(x1 - m);
        float e2 = __expf(x2 - m), e3 = __expf(x3 - m);
        s_alpha[q][lane]       = e0;
        s_alpha[q][lane + 64]  = e1;
        s_alpha[q][lane + 128] = e2;
        s_alpha[q][lane + 192] = e3;
        float s = (e0 + e1) + (e2 + e3);
        #pragma unroll
        for (int off = 32; off >= 1; off >>= 1) s += __shfl_xor(s, off);
        if (lane == 0) s_rsum[q] = 1.f / s;
    }
    __syncthreads();

    // ---- context (partial over 64 t's): ctx[q][i=t] ----
    float ctx[QT];
    #pragma unroll
    for (int q = 0; q < QT; q++) ctx[q] = 0.f;

    const float* krow = keys + ((size_t)b * TH + dg * 64) * DIN + t;
    float ar[QT];
    #pragma unroll
    for (int q = 0; q < QT; q++) ar[q] = s_alpha[q][dg * 64 + lane];

    for (int l = 0; l < 64; l += 4) {
        float kv4[4];
        #pragma unroll
        for (int j = 0; j < 4; j++)
            kv4[j] = krow[(size_t)(l + j) * DIN];
        #pragma unroll
        for (int j = 0; j < 4; j++) {
            #pragma unroll
            for (int q = 0; q < QT; q++)
                ctx[q] = fmaf(readlane_f(ar[q], l + j), kv4[j], ctx[q]);
        }
    }

    #pragma unroll
    for (int q = 0; q < QT; q++) s_part[dg][q][t] = ctx[q];
    __syncthreads();

    // ---- final reduce + normalize + store; exactly 1 (q,i) per thread ----
    {
        int q = tid >> 8, ii = tid & 255;
        float s = s_part[0][q][ii] + s_part[1][q][ii]
                + s_part[2][q][ii] + s_part[3][q][ii];
        out[(size_t)(b * TQn + q0 + q) * DIN + ii] = s * s_rsum[q];
    }
}

// ---------------------------------------------------------------------------
extern "C" void kernel_launch(void* const* d_in, const int* in_sizes, int n_in,
                              void* d_out, int out_size, void* d_ws, size_t ws_size,
                              hipStream_t stream) {
    (void)in_sizes; (void)n_in; (void)out_size; (void)ws_size;
    const float* keys  = (const float*)d_in[0];  // [32*256][256]
    const float* state = (const float*)d_in[1];  // [32*64][256]
    const float* w1    = (const float*)d_in[2];  // [256][256]
    const float* w2    = (const float*)d_in[3];  // [256][256]
    const float* v     = (const float*)d_in[4];  // [256]
    float* out = (float*)d_out;                  // [2048][256]

    float* kpT = (float*)d_ws;                         // 32*256*256 = 8 MB
    float* qp  = kpT + (size_t)BATCH * DD * TH;        // 2048*256   = 2 MB

    hipLaunchKernelGGL(proj_kernel, dim3(640), dim3(256), 0, stream,
                       keys, state, w1, w2, kpT, qp);
    hipLaunchKernelGGL(attn_kernel, dim3(BATCH * (TQn / QT)), dim3(1024), 0, stream,
                       keys, v, kpT, qp, out);
}

// Round 4
// 117.045 us; speedup vs baseline: 1.5562x; 1.0897x over previous
//
#include <hip/hip_runtime.h>
#include <math.h>

#define BATCH 32
#define TH    256
#define TQn   64
#define DIN   256
#define DD    256   // INTERNAL
#define QT    4     // q's per attn block
#define E2C   2.885390081777927f   // 2*log2(e): exp(2x) == exp2(x*E2C)
#define DENMAX 1.0e9f              // den clamp; den^4 <= 1e36 < fp32 max

typedef __attribute__((ext_vector_type(8)))  short bf16x8;   // 8 bf16 = 4 VGPRs
typedef __attribute__((ext_vector_type(16))) float floatx16;

__device__ __forceinline__ float readlane_f(float x, int l) {
    return __int_as_float(__builtin_amdgcn_readlane(__float_as_int(x), l));
}

// exp2(E2C*x) clamped so products stay in fp32 range (2^30 ~ 1.07e9).
__device__ __forceinline__ float eclamp(float x) {
    return __builtin_amdgcn_exp2f(fminf(x * E2C, 30.f));
}

// 2-term bf16 expansion of two floats, packed as (e0 low half | e1 high half).
__device__ __forceinline__ void split2(float x0, float x1, unsigned& hi, unsigned& lo) {
    unsigned u0 = __float_as_uint(x0), u1 = __float_as_uint(x1);
    unsigned h0 = u0 & 0xFFFF0000u,   h1 = u1 & 0xFFFF0000u;
    float r0 = x0 - __uint_as_float(h0);
    float r1 = x1 - __uint_as_float(h1);
    hi = (u0 >> 16) | h1;
    lo = (__float_as_uint(r0) >> 16) | (__float_as_uint(r1) & 0xFFFF0000u);
}

__device__ __forceinline__ void split8(float4 f0, float4 f1, uint4& hi, uint4& lo) {
    split2(f0.x, f0.y, hi.x, lo.x);
    split2(f0.z, f0.w, hi.y, lo.y);
    split2(f1.x, f1.y, hi.z, lo.z);
    split2(f1.z, f1.w, hi.w, lo.w);
}

// ---------------------------------------------------------------------------
// Kernel 1: projections via bf16-split MFMA (3x mfma_f32_32x32x16_bf16).
// NEW: epilogue stores exp2(E2C*proj) (clamped) instead of the raw projection:
//   KtT[b][d][t] = exp2c(kp),  Pq[r][d] = exp2c(qp)
// so the attention score phase needs NO transcendentals per element.
// ---------------------------------------------------------------------------
#define REG4  65                    // uint4 per region (64 + 1 pad)
#define WOFF  (16 * REG4)           // W base in uint4 units
__global__ __launch_bounds__(256, 4)
void proj_kernel(const float* __restrict__ keys,
                 const float* __restrict__ state,
                 const float* __restrict__ w1,
                 const float* __restrict__ w2,
                 float* __restrict__ kpT,
                 float* __restrict__ qpo)
{
    __shared__ uint4 lds4[2 * 16 * REG4];   // 32.5 KB

    const int bid = blockIdx.x;
    const int tid = threadIdx.x;

    const float* X;
    const float* W;
    int m0, n0;
    bool is_kp;
    if (bid < 512) {
        is_kp = true;
        m0 = (bid >> 2) * 64;
        n0 = (bid & 3) * 64;
        X = keys; W = w1;
    } else {
        is_kp = false;
        int lb = bid - 512;
        m0 = (lb >> 2) * 64;
        n0 = (lb & 3) * 64;
        X = state; W = w2;
    }

    const int w    = tid >> 6;        // wave 0..3
    const int l    = tid & 63;
    const int mt   = w >> 1;          // m half-tile
    const int nt   = w & 1;           // n half-tile
    const int srow = tid >> 3;        // 0..31
    const int kg   = tid & 7;         // 0..7
    const int s_s  = kg >> 1;         // k-step 0..3
    const int lidx = (srow & 31) + 32 * (kg & 1);

    floatx16 acc = {};

    for (int k0 = 0; k0 < DIN; k0 += 64) {
        #pragma unroll
        for (int hrow = 0; hrow < 2; hrow++) {
            int m = srow + hrow * 32;
            const float* px = X + (size_t)(m0 + m) * DIN + k0 + kg * 8;
            uint4 hi, lo;
            split8(*(const float4*)px, *(const float4*)(px + 4), hi, lo);
            int g = m >> 5;
            lds4[((0 * 2 + g) * 4 + s_s) * REG4 + lidx] = hi;
            lds4[((2 + g) * 4 + s_s) * REG4 + lidx] = lo;
            const float* pw = W + (size_t)(n0 + m) * DIN + k0 + kg * 8;
            split8(*(const float4*)pw, *(const float4*)(pw + 4), hi, lo);
            lds4[WOFF + ((0 * 2 + g) * 4 + s_s) * REG4 + lidx] = hi;
            lds4[WOFF + ((2 + g) * 4 + s_s) * REG4 + lidx] = lo;
        }
        __syncthreads();

        #pragma unroll
        for (int s = 0; s < 4; s++) {
            uint4 ahr = lds4[((0 * 2 + mt) * 4 + s) * REG4 + l];
            uint4 alr = lds4[((2 + mt) * 4 + s) * REG4 + l];
            uint4 bhr = lds4[WOFF + ((0 * 2 + nt) * 4 + s) * REG4 + l];
            uint4 blr = lds4[WOFF + ((2 + nt) * 4 + s) * REG4 + l];
            bf16x8 ah = __builtin_bit_cast(bf16x8, ahr);
            bf16x8 al = __builtin_bit_cast(bf16x8, alr);
            bf16x8 bh = __builtin_bit_cast(bf16x8, bhr);
            bf16x8 bl = __builtin_bit_cast(bf16x8, blr);
            acc = __builtin_amdgcn_mfma_f32_32x32x16_bf16(ah, bh, acc, 0, 0, 0);
            acc = __builtin_amdgcn_mfma_f32_32x32x16_bf16(al, bh, acc, 0, 0, 0);
            acc = __builtin_amdgcn_mfma_f32_32x32x16_bf16(ah, bl, acc, 0, 0, 0);
        }
        __syncthreads();
    }

    // C/D: col=l&31 (n), row=(r&3)+8*(r>>2)+4*(l>>5) (m); store exp2c(value)
    const int col = l & 31;
    const int hl  = l >> 5;
    if (is_kp) {
        const int b  = m0 >> 8;
        const int tb = (m0 & 255) + mt * 32 + 4 * hl;
        const int d  = n0 + nt * 32 + col;
        float* p = kpT + ((size_t)b * DD + d) * TH + tb;
        #pragma unroll
        for (int g = 0; g < 4; g++)
            *(float4*)(p + 8 * g) = make_float4(eclamp(acc[4*g]),   eclamp(acc[4*g+1]),
                                                eclamp(acc[4*g+2]), eclamp(acc[4*g+3]));
    } else {
        const int d = n0 + nt * 32 + col;
        #pragma unroll
        for (int r = 0; r < 16; r++) {
            int row = (r & 3) + 8 * (r >> 2) + 4 * hl;
            qpo[(size_t)(m0 + mt * 32 + row) * DD + d] = eclamp(acc[r]);
        }
    }
}

// ---------------------------------------------------------------------------
// Kernel 2: fused scores + softmax + context. 1024 threads, grid 512.
// Score phase: sigma-sum via factorized exp + rational tree-combine:
//   T(q,t) = sum_d v_d / (1 + Pq[q,d]*Kt[d,t]);  softmax input = -2T.
// Per 4 d's: 4 fma + 4 min + 9 combine ops + 1 rcp (no exp!). Pq, v come in
// on the SCALAR pipe (readfirstlane'd base -> s_load), kv coalesced vector.
// ---------------------------------------------------------------------------
__global__ __launch_bounds__(1024, 8)
void attn_kernel(const float* __restrict__ keys,
                 const float* __restrict__ vvec,
                 const float* __restrict__ kpT,
                 const float* __restrict__ qp,
                 float* __restrict__ out)
{
    __shared__ float s_part[4][QT][TH];   // 16 KB
    __shared__ float s_alpha[QT][TH];     // 4 KB
    __shared__ float s_rsum[QT];

    const int bid  = blockIdx.x;
    const int b    = bid & 31;            // bid%8 == b%8 -> XCD-local batch
    const int q0   = (bid >> 5) * QT;
    const int tid  = threadIdx.x;
    const int t    = tid & 255;
    const int dgu  = __builtin_amdgcn_readfirstlane(tid >> 8);  // wave-uniform
    const int lane = tid & 63;
    const int wv   = tid >> 6;

    // ---- scores (partial over this wave-group's 64 d's) ----
    float acc[QT];
    #pragma unroll
    for (int q = 0; q < QT; q++) acc[q] = 0.f;

    const float* kbase = kpT + ((size_t)b * DD + dgu * 64) * TH + t;   // Kt, lane=t
    const float* qpb   = qp + (size_t)(b * TQn + q0) * DD + dgu * 64;  // Pq, uniform
    const float* vv    = vvec + dgu * 64;                              // uniform

    #pragma unroll 4
    for (int l0 = 0; l0 < 64; l0 += 4) {
        float kv0 = kbase[(size_t)(l0 + 0) * TH];
        float kv1 = kbase[(size_t)(l0 + 1) * TH];
        float kv2 = kbase[(size_t)(l0 + 2) * TH];
        float kv3 = kbase[(size_t)(l0 + 3) * TH];
        float v0 = vv[l0 + 0], v1 = vv[l0 + 1], v2 = vv[l0 + 2], v3 = vv[l0 + 3];
        #pragma unroll
        for (int q = 0; q < QT; q++) {
            float d0 = fminf(fmaf(qpb[q * DD + l0 + 0], kv0, 1.f), DENMAX);
            float d1 = fminf(fmaf(qpb[q * DD + l0 + 1], kv1, 1.f), DENMAX);
            float d2 = fminf(fmaf(qpb[q * DD + l0 + 2], kv2, 1.f), DENMAX);
            float d3 = fminf(fmaf(qpb[q * DD + l0 + 3], kv3, 1.f), DENMAX);
            // sum v_j/d_j as one rational: exact algebra, 1 rcp per 4 terms
            float n01 = fmaf(v1, d0, v0 * d1);
            float d01 = d0 * d1;
            float n23 = fmaf(v3, d2, v2 * d3);
            float d23 = d2 * d3;
            float num = fmaf(n23, d01, n01 * d23);
            float den = d01 * d23;
            acc[q] = fmaf(num, __builtin_amdgcn_rcpf(den), acc[q]);
        }
    }

    #pragma unroll
    for (int q = 0; q < QT; q++) s_part[dgu][q][t] = acc[q];
    __syncthreads();

    // ---- softmax over t=256; wave wv (<QT) handles q=wv ----
    if (wv < QT) {
        const int q = wv;
        float x0, x1, x2, x3;
        {
            float p0 = s_part[0][q][lane]       + s_part[1][q][lane]
                     + s_part[2][q][lane]       + s_part[3][q][lane];
            float p1 = s_part[0][q][lane + 64]  + s_part[1][q][lane + 64]
                     + s_part[2][q][lane + 64]  + s_part[3][q][lane + 64];
            float p2 = s_part[0][q][lane + 128] + s_part[1][q][lane + 128]
                     + s_part[2][q][lane + 128] + s_part[3][q][lane + 128];
            float p3 = s_part[0][q][lane + 192] + s_part[1][q][lane + 192]
                     + s_part[2][q][lane + 192] + s_part[3][q][lane + 192];
            x0 = -2.f * p0; x1 = -2.f * p1; x2 = -2.f * p2; x3 = -2.f * p3;
        }
        float m = fmaxf(fmaxf(x0, x1), fmaxf(x2, x3));
        #pragma unroll
        for (int off = 32; off >= 1; off >>= 1) m = fmaxf(m, __shfl_xor(m, off));
        float e0 = __expf(x0 - m), e1 = __expf(x1 - m);
        float e2 = __expf(x2 - m), e3 = __expf(x3 - m);
        s_alpha[q][lane]       = e0;
        s_alpha[q][lane + 64]  = e1;
        s_alpha[q][lane + 128] = e2;
        s_alpha[q][lane + 192] = e3;
        float s = (e0 + e1) + (e2 + e3);
        #pragma unroll
        for (int off = 32; off >= 1; off >>= 1) s += __shfl_xor(s, off);
        if (lane == 0) s_rsum[q] = 1.f / s;
    }
    __syncthreads();

    // ---- context (partial over this wave-group's 64 t's): ctx[q][i=t] ----
    float ctx[QT];
    #pragma unroll
    for (int q = 0; q < QT; q++) ctx[q] = 0.f;

    const float* krow = keys + ((size_t)b * TH + dgu * 64) * DIN + t;
    float ar[QT];
    #pragma unroll
    for (int q = 0; q < QT; q++) ar[q] = s_alpha[q][dgu * 64 + lane];

    for (int l = 0; l < 64; l += 4) {
        float kv4[4];
        #pragma unroll
        for (int j = 0; j < 4; j++)
            kv4[j] = krow[(size_t)(l + j) * DIN];
        #pragma unroll
        for (int j = 0; j < 4; j++) {
            #pragma unroll
            for (int q = 0; q < QT; q++)
                ctx[q] = fmaf(readlane_f(ar[q], l + j), kv4[j], ctx[q]);
        }
    }

    #pragma unroll
    for (int q = 0; q < QT; q++) s_part[dgu][q][t] = ctx[q];
    __syncthreads();

    // ---- final reduce + normalize + store; exactly 1 (q,i) per thread ----
    {
        int q = tid >> 8, ii = tid & 255;
        float s = s_part[0][q][ii] + s_part[1][q][ii]
                + s_part[2][q][ii] + s_part[3][q][ii];
        out[(size_t)(b * TQn + q0 + q) * DIN + ii] = s * s_rsum[q];
    }
}

// ---------------------------------------------------------------------------
extern "C" void kernel_launch(void* const* d_in, const int* in_sizes, int n_in,
                              void* d_out, int out_size, void* d_ws, size_t ws_size,
                              hipStream_t stream) {
    (void)in_sizes; (void)n_in; (void)out_size; (void)ws_size;
    const float* keys  = (const float*)d_in[0];  // [32*256][256]
    const float* state = (const float*)d_in[1];  // [32*64][256]
    const float* w1    = (const float*)d_in[2];  // [256][256]
    const float* w2    = (const float*)d_in[3];  // [256][256]
    const float* v     = (const float*)d_in[4];  // [256]
    float* out = (float*)d_out;                  // [2048][256]

    float* kpT = (float*)d_ws;                         // KtT: 32*256*256 = 8 MB
    float* qp  = kpT + (size_t)BATCH * DD * TH;        // Pq:  2048*256   = 2 MB

    hipLaunchKernelGGL(proj_kernel, dim3(640), dim3(256), 0, stream,
                       keys, state, w1, w2, kpT, qp);
    hipLaunchKernelGGL(attn_kernel, dim3(BATCH * (TQn / QT)), dim3(1024), 0, stream,
                       keys, v, kpT, qp, out);
}